// Round 1
// baseline (311.779 us; speedup 1.0000x reference)
//
#include <hip/hip_runtime.h>
#include <hip/hip_bf16.h>

// GatedMoE: B=8, T=4096, D=128, E=16, TOP_K=2  (all f32)
// out = concat(weighted_avg [NTOK*128], consensus [NTOK])
#define NTOK 32768
#define DD 128
#define NE 16

// ws layout (bytes); total ~36 MiB
#define OFF_COUNTS 0                     // 16 * int
#define OFF_TOKW   (4*1024)              // NTOK*2 f32  = 256 KiB
#define OFF_LISTS  (512*1024)            // NE*NTOK int = 2 MiB
#define OFF_YBUF   (4*1024*1024)         // NTOK*2*128 f32 = 32 MiB

// ---------------- Kernel 1: gating (softmax + top2 + expert list scatter) ----
__global__ __launch_bounds__(256) void gate_kernel(
    const float* __restrict__ x, const float* __restrict__ Wg,
    const float* __restrict__ bg,
    int* __restrict__ counts, int* __restrict__ lists, float* __restrict__ tokw)
{
    __shared__ float sWg[DD * NE];   // 8 KiB
    const int tid = threadIdx.x;
    for (int i = tid; i < DD * NE; i += 256) sWg[i] = Wg[i];
    __syncthreads();

    const int t = blockIdx.x * 256 + tid;
    const float* xt = x + (size_t)t * DD;

    float logits[NE];
    #pragma unroll
    for (int e = 0; e < NE; ++e) logits[e] = bg[e];

    for (int d4 = 0; d4 < DD / 4; ++d4) {
        float4 xv = ((const float4*)xt)[d4];
        float xs0 = xv.x, xs1 = xv.y, xs2 = xv.z, xs3 = xv.w;
        const float* w0 = &sWg[(d4 * 4 + 0) * NE];
        const float* w1 = &sWg[(d4 * 4 + 1) * NE];
        const float* w2 = &sWg[(d4 * 4 + 2) * NE];
        const float* w3 = &sWg[(d4 * 4 + 3) * NE];
        #pragma unroll
        for (int e = 0; e < NE; ++e) {
            float acc = logits[e];
            acc = fmaf(xs0, w0[e], acc);
            acc = fmaf(xs1, w1[e], acc);
            acc = fmaf(xs2, w2[e], acc);
            acc = fmaf(xs3, w3[e], acc);
            logits[e] = acc;
        }
    }

    // softmax pieces
    float m = logits[0];
    #pragma unroll
    for (int e = 1; e < NE; ++e) m = fmaxf(m, logits[e]);
    float Z = 0.0f;
    #pragma unroll
    for (int e = 0; e < NE; ++e) Z += expf(logits[e] - m);

    // top-2 on logits (monotone with softmax). Strict > keeps lowest index on ties,
    // matching jax.lax.top_k ordering.
    int i1 = 0; float l1 = logits[0];
    #pragma unroll
    for (int e = 1; e < NE; ++e) if (logits[e] > l1) { l1 = logits[e]; i1 = e; }
    int i2 = -1; float l2 = -3.4e38f;
    #pragma unroll
    for (int e = 0; e < NE; ++e) if (e != i1 && logits[e] > l2) { l2 = logits[e]; i2 = e; }

    float p1 = expf(l1 - m) / Z;
    float p2 = expf(l2 - m) / Z;
    float s  = p1 + p2 + 1e-6f;
    float w1v = p1 / s, w2v = p2 / s;
    tokw[t * 2 + 0] = w1v;
    tokw[t * 2 + 1] = w2v;

    int s1 = atomicAdd(&counts[i1], 1);
    lists[i1 * NTOK + s1] = t * 2 + 0;
    int s2 = atomicAdd(&counts[i2], 1);
    lists[i2 * NTOK + s2] = t * 2 + 1;
}

// ---------------- Kernel 2: grouped per-expert GEMM (f32, exact) -------------
// grid = (NTOK/64, NE); block = 256 (4 waves). Each block: 64 tokens of expert e.
// Wave tiling: lane = tq*16 + o4 ; wave covers 16 tokens x 128 outputs;
// each lane: 4 tokens x 8 outputs in registers.
__global__ __launch_bounds__(256) void expert_kernel(
    const float* __restrict__ x, const float* __restrict__ Ew,
    const int* __restrict__ counts, const int* __restrict__ lists,
    float* __restrict__ ybuf)
{
    const int e = blockIdx.y;
    const int count = counts[e];
    const int start = blockIdx.x * 64;
    if (start >= count) return;

    __shared__ int   sEnt[64];
    __shared__ float xs[DD][64];     // 32 KiB, transposed X tile [d][tok]
    __shared__ float ews[32][DD];    // 16 KiB, k-tile of Ew[e]

    const int tid = threadIdx.x;
    if (tid < 64) {
        int idx = start + tid;
        sEnt[tid] = (idx < count) ? lists[e * NTOK + idx] : -1;
    }
    __syncthreads();

    // gather X tile (transposed into LDS)
    for (int i = tid; i < 64 * 32; i += 256) {
        int tok = i & 63, d4 = i >> 6;
        int en = sEnt[tok];
        if (en >= 0) {
            float4 v = ((const float4*)(x + (size_t)(en >> 1) * DD))[d4];
            xs[d4 * 4 + 0][tok] = v.x;
            xs[d4 * 4 + 1][tok] = v.y;
            xs[d4 * 4 + 2][tok] = v.z;
            xs[d4 * 4 + 3][tok] = v.w;
        }
    }

    const int lane = tid & 63, wv = tid >> 6;
    const int o4 = lane & 15, tq = lane >> 4;
    const int tokb = wv * 16 + tq * 4;

    float acc[4][8];
    #pragma unroll
    for (int a = 0; a < 4; ++a)
        #pragma unroll
        for (int b = 0; b < 8; ++b) acc[a][b] = 0.0f;

    const float* EwE = Ew + (size_t)e * DD * DD;

    for (int kt = 0; kt < 4; ++kt) {
        __syncthreads();   // xs ready (1st iter) / old ews fully consumed
        for (int i = tid; i < 32 * 32; i += 256) {          // 1024 float4s
            int row = i >> 5, c4 = i & 31;
            ((float4*)&ews[row][0])[c4] =
                ((const float4*)(EwE + (size_t)(kt * 32 + row) * DD))[c4];
        }
        __syncthreads();

        #pragma unroll 4
        for (int d = 0; d < 32; ++d) {
            float4 xv = *(const float4*)&xs[kt * 32 + d][tokb];
            float4 e0 = *(const float4*)&ews[d][o4 * 8];
            float4 e1 = *(const float4*)&ews[d][o4 * 8 + 4];
            float xt0 = xv.x, xt1 = xv.y, xt2 = xv.z, xt3 = xv.w;
            acc[0][0] = fmaf(xt0, e0.x, acc[0][0]); acc[0][1] = fmaf(xt0, e0.y, acc[0][1]);
            acc[0][2] = fmaf(xt0, e0.z, acc[0][2]); acc[0][3] = fmaf(xt0, e0.w, acc[0][3]);
            acc[0][4] = fmaf(xt0, e1.x, acc[0][4]); acc[0][5] = fmaf(xt0, e1.y, acc[0][5]);
            acc[0][6] = fmaf(xt0, e1.z, acc[0][6]); acc[0][7] = fmaf(xt0, e1.w, acc[0][7]);
            acc[1][0] = fmaf(xt1, e0.x, acc[1][0]); acc[1][1] = fmaf(xt1, e0.y, acc[1][1]);
            acc[1][2] = fmaf(xt1, e0.z, acc[1][2]); acc[1][3] = fmaf(xt1, e0.w, acc[1][3]);
            acc[1][4] = fmaf(xt1, e1.x, acc[1][4]); acc[1][5] = fmaf(xt1, e1.y, acc[1][5]);
            acc[1][6] = fmaf(xt1, e1.z, acc[1][6]); acc[1][7] = fmaf(xt1, e1.w, acc[1][7]);
            acc[2][0] = fmaf(xt2, e0.x, acc[2][0]); acc[2][1] = fmaf(xt2, e0.y, acc[2][1]);
            acc[2][2] = fmaf(xt2, e0.z, acc[2][2]); acc[2][3] = fmaf(xt2, e0.w, acc[2][3]);
            acc[2][4] = fmaf(xt2, e1.x, acc[2][4]); acc[2][5] = fmaf(xt2, e1.y, acc[2][5]);
            acc[2][6] = fmaf(xt2, e1.z, acc[2][6]); acc[2][7] = fmaf(xt2, e1.w, acc[2][7]);
            acc[3][0] = fmaf(xt3, e0.x, acc[3][0]); acc[3][1] = fmaf(xt3, e0.y, acc[3][1]);
            acc[3][2] = fmaf(xt3, e0.z, acc[3][2]); acc[3][3] = fmaf(xt3, e0.w, acc[3][3]);
            acc[3][4] = fmaf(xt3, e1.x, acc[3][4]); acc[3][5] = fmaf(xt3, e1.y, acc[3][5]);
            acc[3][6] = fmaf(xt3, e1.z, acc[3][6]); acc[3][7] = fmaf(xt3, e1.w, acc[3][7]);
        }
    }

    #pragma unroll
    for (int tt = 0; tt < 4; ++tt) {
        int en = sEnt[tokb + tt];
        if (en >= 0) {
            float* yr = ybuf + (size_t)en * DD + o4 * 8;
            float4 a; a.x = acc[tt][0]; a.y = acc[tt][1]; a.z = acc[tt][2]; a.w = acc[tt][3];
            float4 b; b.x = acc[tt][4]; b.y = acc[tt][5]; b.z = acc[tt][6]; b.w = acc[tt][7];
            *(float4*)yr = a;
            *(float4*)(yr + 4) = b;
        }
    }
}

// ---------------- Kernel 3: combine (avg, var, consensus) -------------------
// block = 256 = 4 waves; one wave per token; lane handles 2 dims (float2).
__global__ __launch_bounds__(256) void combine_kernel(
    const float* __restrict__ ybuf, const float* __restrict__ tokw,
    float* __restrict__ avg_out, float* __restrict__ cons_out)
{
    const int tid = threadIdx.x;
    const int lane = tid & 63, wv = tid >> 6;
    const int t = blockIdx.x * 4 + wv;

    const float w1 = tokw[t * 2 + 0];
    const float w2 = tokw[t * 2 + 1];
    const float2 y1 = ((const float2*)(ybuf + (size_t)(t * 2 + 0) * DD))[lane];
    const float2 y2 = ((const float2*)(ybuf + (size_t)(t * 2 + 1) * DD))[lane];

    float a0 = w1 * y1.x + w2 * y2.x;
    float a1 = w1 * y1.y + w2 * y2.y;
    float2 av; av.x = a0; av.y = a1;
    ((float2*)(avg_out + (size_t)t * DD))[lane] = av;

    float d10 = y1.x - a0, d11 = y1.y - a1;
    float d20 = y2.x - a0, d21 = y2.y - a1;
    float v = w1 * (d10 * d10 + d11 * d11) + w2 * (d20 * d20 + d21 * d21);
    #pragma unroll
    for (int off = 32; off > 0; off >>= 1) v += __shfl_xor(v, off);
    if (lane == 0) cons_out[t] = expf(-v * (1.0f / 128.0f));
}

// ---------------- launcher ---------------------------------------------------
extern "C" void kernel_launch(void* const* d_in, const int* in_sizes, int n_in,
                              void* d_out, int out_size, void* d_ws, size_t ws_size,
                              hipStream_t stream)
{
    const float* x  = (const float*)d_in[0];
    const float* Wg = (const float*)d_in[1];
    const float* bg = (const float*)d_in[2];
    const float* Ew = (const float*)d_in[3];
    float* out = (float*)d_out;

    char* ws = (char*)d_ws;
    int*   counts = (int*)(ws + OFF_COUNTS);
    float* tokw   = (float*)(ws + OFF_TOKW);
    int*   lists  = (int*)(ws + OFF_LISTS);
    float* ybuf   = (float*)(ws + OFF_YBUF);

    hipMemsetAsync(counts, 0, NE * sizeof(int), stream);

    gate_kernel<<<NTOK / 256, 256, 0, stream>>>(x, Wg, bg, counts, lists, tokw);
    expert_kernel<<<dim3(NTOK / 64, NE), 256, 0, stream>>>(x, Ew, counts, lists, ybuf);
    combine_kernel<<<NTOK / 4, 256, 0, stream>>>(ybuf, tokw, out, out + (size_t)NTOK * DD);
}

// Round 2
// 134.181 us; speedup vs baseline: 2.3236x; 2.3236x over previous
//
#include <hip/hip_runtime.h>
#include <hip/hip_bf16.h>

// GatedMoE: B=8, T=4096, D=128, E=16, TOP_K=2  (all f32)
// out = concat(weighted_avg [NTOK*128], consensus [NTOK])
#define NTOK 32768
#define DD 128
#define NE 16
#define CSTRIDE 32   // pad each expert counter to its own 128B line

// ws layout (bytes); total ~36 MiB
#define OFF_COUNTS 0                     // NE*CSTRIDE ints = 2 KiB
#define OFF_TOKW   (4*1024)              // NTOK*2 f32  = 256 KiB
#define OFF_LISTS  (512*1024)            // NE*NTOK int = 2 MiB
#define OFF_YBUF   (4*1024*1024)         // NTOK*2*128 f32 = 32 MiB

// ---------------- Kernel 1: gating (softmax + top2 + expert list scatter) ----
// 128 threads/block, 1 token/thread, 256 blocks. Atomics aggregated in LDS,
// one global atomic per (block, expert) onto line-padded counters.
__global__ __launch_bounds__(128) void gate_kernel(
    const float* __restrict__ x, const float* __restrict__ Wg,
    const float* __restrict__ bg,
    int* __restrict__ counts, int* __restrict__ lists, float* __restrict__ tokw)
{
    __shared__ float sWg[DD * NE];   // 8 KiB
    __shared__ int   sCnt[NE];
    __shared__ int   sBase[NE];
    const int tid = threadIdx.x;
    for (int i = tid; i < DD * NE; i += 128) sWg[i] = Wg[i];
    if (tid < NE) sCnt[tid] = 0;
    __syncthreads();

    const int t = blockIdx.x * 128 + tid;
    const float* xt = x + (size_t)t * DD;

    float logits[NE];
    #pragma unroll
    for (int e = 0; e < NE; ++e) logits[e] = bg[e];

    #pragma unroll 4
    for (int d4 = 0; d4 < DD / 4; ++d4) {
        float4 xv = ((const float4*)xt)[d4];
        float xs0 = xv.x, xs1 = xv.y, xs2 = xv.z, xs3 = xv.w;
        const float* w0 = &sWg[(d4 * 4 + 0) * NE];
        const float* w1 = &sWg[(d4 * 4 + 1) * NE];
        const float* w2 = &sWg[(d4 * 4 + 2) * NE];
        const float* w3 = &sWg[(d4 * 4 + 3) * NE];
        #pragma unroll
        for (int e = 0; e < NE; ++e) {
            float acc = logits[e];
            acc = fmaf(xs0, w0[e], acc);
            acc = fmaf(xs1, w1[e], acc);
            acc = fmaf(xs2, w2[e], acc);
            acc = fmaf(xs3, w3[e], acc);
            logits[e] = acc;
        }
    }

    // softmax pieces
    float m = logits[0];
    #pragma unroll
    for (int e = 1; e < NE; ++e) m = fmaxf(m, logits[e]);
    float Z = 0.0f;
    #pragma unroll
    for (int e = 0; e < NE; ++e) Z += expf(logits[e] - m);

    // top-2 on logits (monotone with softmax); strict > keeps lowest index on ties
    int i1 = 0; float l1 = logits[0];
    #pragma unroll
    for (int e = 1; e < NE; ++e) if (logits[e] > l1) { l1 = logits[e]; i1 = e; }
    int i2 = -1; float l2 = -3.4e38f;
    #pragma unroll
    for (int e = 0; e < NE; ++e) if (e != i1 && logits[e] > l2) { l2 = logits[e]; i2 = e; }

    float p1 = expf(l1 - m) / Z;
    float p2 = expf(l2 - m) / Z;
    float s  = p1 + p2 + 1e-6f;
    tokw[t * 2 + 0] = p1 / s;
    tokw[t * 2 + 1] = p2 / s;

    // LDS-aggregated expert list build
    int s1 = atomicAdd(&sCnt[i1], 1);
    int s2 = atomicAdd(&sCnt[i2], 1);
    __syncthreads();
    if (tid < NE) sBase[tid] = atomicAdd(&counts[tid * CSTRIDE], sCnt[tid]);
    __syncthreads();
    lists[i1 * NTOK + sBase[i1] + s1] = t * 2 + 0;
    lists[i2 * NTOK + sBase[i2] + s2] = t * 2 + 1;
}

// ---------------- Kernel 2: grouped per-expert GEMM (f32, exact) -------------
// grid = (NTOK/64, NE); block = 256 (4 waves). Each block: 64 tokens of expert e.
// lane = tq*16 + o4; lane's 8 output cols are {o4*4..o4*4+3} and {o4*4+64..+67}
// (16B stride across 16 lanes -> 2-way LDS bank aliasing = free, vs 4-way before).
__global__ __launch_bounds__(256) void expert_kernel(
    const float* __restrict__ x, const float* __restrict__ Ew,
    const int* __restrict__ counts, const int* __restrict__ lists,
    float* __restrict__ ybuf)
{
    const int e = blockIdx.y;
    const int count = counts[e * CSTRIDE];
    const int start = blockIdx.x * 64;
    if (start >= count) return;

    __shared__ int   sEnt[64];
    __shared__ float xs[DD][64];     // 32 KiB, transposed X tile [d][tok]
    __shared__ float ews[32][DD];    // 16 KiB, k-tile of Ew[e]

    const int tid = threadIdx.x;
    if (tid < 64) {
        int idx = start + tid;
        sEnt[tid] = (idx < count) ? lists[e * NTOK + idx] : -1;
    }
    __syncthreads();

    // gather X tile (transposed into LDS); tok==lane -> conflict-free ds_write
    for (int i = tid; i < 64 * 32; i += 256) {
        int tok = i & 63, d4 = i >> 6;
        int en = sEnt[tok];
        if (en >= 0) {
            float4 v = ((const float4*)(x + (size_t)(en >> 1) * DD))[d4];
            xs[d4 * 4 + 0][tok] = v.x;
            xs[d4 * 4 + 1][tok] = v.y;
            xs[d4 * 4 + 2][tok] = v.z;
            xs[d4 * 4 + 3][tok] = v.w;
        }
    }

    const int lane = tid & 63, wv = tid >> 6;
    const int o4 = lane & 15, tq = lane >> 4;
    const int tokb = wv * 16 + tq * 4;
    const int colb = o4 * 4;

    float acc[4][8];
    #pragma unroll
    for (int a = 0; a < 4; ++a)
        #pragma unroll
        for (int b = 0; b < 8; ++b) acc[a][b] = 0.0f;

    const float* EwE = Ew + (size_t)e * DD * DD;

    for (int kt = 0; kt < 4; ++kt) {
        __syncthreads();   // xs ready (1st iter) / old ews fully consumed
        for (int i = tid; i < 32 * 32; i += 256) {          // 1024 float4s
            int row = i >> 5, c4 = i & 31;
            ((float4*)&ews[row][0])[c4] =
                ((const float4*)(EwE + (size_t)(kt * 32 + row) * DD))[c4];
        }
        __syncthreads();

        #pragma unroll 4
        for (int d = 0; d < 32; ++d) {
            float4 xv = *(const float4*)&xs[kt * 32 + d][tokb];
            float4 e0 = *(const float4*)&ews[d][colb];        // banks o4*4 -> 2-way
            float4 e1 = *(const float4*)&ews[d][colb + 64];
            float xt0 = xv.x, xt1 = xv.y, xt2 = xv.z, xt3 = xv.w;
            acc[0][0] = fmaf(xt0, e0.x, acc[0][0]); acc[0][1] = fmaf(xt0, e0.y, acc[0][1]);
            acc[0][2] = fmaf(xt0, e0.z, acc[0][2]); acc[0][3] = fmaf(xt0, e0.w, acc[0][3]);
            acc[0][4] = fmaf(xt0, e1.x, acc[0][4]); acc[0][5] = fmaf(xt0, e1.y, acc[0][5]);
            acc[0][6] = fmaf(xt0, e1.z, acc[0][6]); acc[0][7] = fmaf(xt0, e1.w, acc[0][7]);
            acc[1][0] = fmaf(xt1, e0.x, acc[1][0]); acc[1][1] = fmaf(xt1, e0.y, acc[1][1]);
            acc[1][2] = fmaf(xt1, e0.z, acc[1][2]); acc[1][3] = fmaf(xt1, e0.w, acc[1][3]);
            acc[1][4] = fmaf(xt1, e1.x, acc[1][4]); acc[1][5] = fmaf(xt1, e1.y, acc[1][5]);
            acc[1][6] = fmaf(xt1, e1.z, acc[1][6]); acc[1][7] = fmaf(xt1, e1.w, acc[1][7]);
            acc[2][0] = fmaf(xt2, e0.x, acc[2][0]); acc[2][1] = fmaf(xt2, e0.y, acc[2][1]);
            acc[2][2] = fmaf(xt2, e0.z, acc[2][2]); acc[2][3] = fmaf(xt2, e0.w, acc[2][3]);
            acc[2][4] = fmaf(xt2, e1.x, acc[2][4]); acc[2][5] = fmaf(xt2, e1.y, acc[2][5]);
            acc[2][6] = fmaf(xt2, e1.z, acc[2][6]); acc[2][7] = fmaf(xt2, e1.w, acc[2][7]);
            acc[3][0] = fmaf(xt3, e0.x, acc[3][0]); acc[3][1] = fmaf(xt3, e0.y, acc[3][1]);
            acc[3][2] = fmaf(xt3, e0.z, acc[3][2]); acc[3][3] = fmaf(xt3, e0.w, acc[3][3]);
            acc[3][4] = fmaf(xt3, e1.x, acc[3][4]); acc[3][5] = fmaf(xt3, e1.y, acc[3][5]);
            acc[3][6] = fmaf(xt3, e1.z, acc[3][6]); acc[3][7] = fmaf(xt3, e1.w, acc[3][7]);
        }
    }

    #pragma unroll
    for (int tt = 0; tt < 4; ++tt) {
        int en = sEnt[tokb + tt];
        if (en >= 0) {
            float* yr = ybuf + (size_t)en * DD;
            float4 a; a.x = acc[tt][0]; a.y = acc[tt][1]; a.z = acc[tt][2]; a.w = acc[tt][3];
            float4 b; b.x = acc[tt][4]; b.y = acc[tt][5]; b.z = acc[tt][6]; b.w = acc[tt][7];
            *(float4*)(yr + colb)      = a;
            *(float4*)(yr + colb + 64) = b;
        }
    }
}

// ---------------- Kernel 3: combine (avg, var, consensus) -------------------
// block = 256 = 4 waves; one wave per token; lane handles 2 dims (float2).
__global__ __launch_bounds__(256) void combine_kernel(
    const float* __restrict__ ybuf, const float* __restrict__ tokw,
    float* __restrict__ avg_out, float* __restrict__ cons_out)
{
    const int tid = threadIdx.x;
    const int lane = tid & 63, wv = tid >> 6;
    const int t = blockIdx.x * 4 + wv;

    const float w1 = tokw[t * 2 + 0];
    const float w2 = tokw[t * 2 + 1];
    const float2 y1 = ((const float2*)(ybuf + (size_t)(t * 2 + 0) * DD))[lane];
    const float2 y2 = ((const float2*)(ybuf + (size_t)(t * 2 + 1) * DD))[lane];

    float a0 = w1 * y1.x + w2 * y2.x;
    float a1 = w1 * y1.y + w2 * y2.y;
    float2 av; av.x = a0; av.y = a1;
    ((float2*)(avg_out + (size_t)t * DD))[lane] = av;

    float d10 = y1.x - a0, d11 = y1.y - a1;
    float d20 = y2.x - a0, d21 = y2.y - a1;
    float v = w1 * (d10 * d10 + d11 * d11) + w2 * (d20 * d20 + d21 * d21);
    #pragma unroll
    for (int off = 32; off > 0; off >>= 1) v += __shfl_xor(v, off);
    if (lane == 0) cons_out[t] = expf(-v * (1.0f / 128.0f));
}

// ---------------- launcher ---------------------------------------------------
extern "C" void kernel_launch(void* const* d_in, const int* in_sizes, int n_in,
                              void* d_out, int out_size, void* d_ws, size_t ws_size,
                              hipStream_t stream)
{
    const float* x  = (const float*)d_in[0];
    const float* Wg = (const float*)d_in[1];
    const float* bg = (const float*)d_in[2];
    const float* Ew = (const float*)d_in[3];
    float* out = (float*)d_out;

    char* ws = (char*)d_ws;
    int*   counts = (int*)(ws + OFF_COUNTS);
    float* tokw   = (float*)(ws + OFF_TOKW);
    int*   lists  = (int*)(ws + OFF_LISTS);
    float* ybuf   = (float*)(ws + OFF_YBUF);

    hipMemsetAsync(counts, 0, NE * CSTRIDE * sizeof(int), stream);

    gate_kernel<<<NTOK / 128, 128, 0, stream>>>(x, Wg, bg, counts, lists, tokw);
    expert_kernel<<<dim3(NTOK / 64, NE), 256, 0, stream>>>(x, Ew, counts, lists, ybuf);
    combine_kernel<<<NTOK / 4, 256, 0, stream>>>(ybuf, tokw, out, out + (size_t)NTOK * DD);
}

// Round 4
// 125.017 us; speedup vs baseline: 2.4939x; 1.0733x over previous
//
#include <hip/hip_runtime.h>
#include <hip/hip_bf16.h>

// GatedMoE: B=8, T=4096, D=128, E=16, TOP_K=2 (f32 in/out, bf16 MFMA inside)
// out = concat(weighted_avg [NTOK*128] f32, consensus [NTOK] f32)
#define NTOK 32768
#define DD 128
#define NE 16
#define CSTRIDE 32   // pad each expert counter to its own 128B line

// ws layout (bytes); total 28 MiB (<=36 MiB proven safe)
#define OFF_COUNTS 0                     // NE*CSTRIDE ints = 2 KiB
#define OFF_TOKW   (4*1024)              // NTOK*2 f32  = 256 KiB
#define OFF_LISTS  (512*1024)            // NE*NTOK int = 2 MiB
#define OFF_XB     (3*1024*1024)         // NTOK*128 bf16 = 8 MiB
#define OFF_EWT    (11*1024*1024)        // NE*128*128 bf16 = 512 KiB
#define OFF_YBUF   (12*1024*1024)        // NTOK*2*128 bf16 = 16 MiB

typedef __attribute__((ext_vector_type(8))) short bf16x8;
typedef __attribute__((ext_vector_type(4))) float f32x4;

static __device__ inline ushort f2bf(float f) {      // RNE f32 -> bf16 bits
    uint u = __builtin_bit_cast(uint, f);
    u = u + 0x7FFFu + ((u >> 16) & 1u);
    return (ushort)(u >> 16);
}
static __device__ inline float b2f(ushort h) {
    uint u = ((uint)h) << 16;
    return __builtin_bit_cast(float, u);
}

// ---------------- Kernel 0: Ew f32[k][o] -> EwT bf16[o][k] ------------------
// grid = 256 blocks (16 experts x 16 tiles of 32x32), 256 threads.
__global__ __launch_bounds__(256) void ewt_kernel(
    const float* __restrict__ Ew, ushort* __restrict__ ewT)
{
    __shared__ float tile[32][33];
    const int b = blockIdx.x;
    const int e = b >> 4, ki = ((b >> 2) & 3) * 32, oi = (b & 3) * 32;
    const int tid = threadIdx.x;
    const int r = tid >> 3, c4 = (tid & 7) * 4;
    const float4 v = *(const float4*)(Ew + (size_t)e * DD * DD + (ki + r) * DD + oi + c4);
    tile[r][c4 + 0] = v.x; tile[r][c4 + 1] = v.y;
    tile[r][c4 + 2] = v.z; tile[r][c4 + 3] = v.w;
    __syncthreads();
    const int o = tid >> 3, k4 = (tid & 7) * 4;
    ushort4 s;
    s.x = f2bf(tile[k4 + 0][o]);
    s.y = f2bf(tile[k4 + 1][o]);
    s.z = f2bf(tile[k4 + 2][o]);
    s.w = f2bf(tile[k4 + 3][o]);
    *(ushort4*)(ewT + (size_t)e * DD * DD + (oi + o) * DD + ki + k4) = s;
}

// ---------------- Kernel 1: gating + x->bf16 --------------------------------
// 4 lanes per token; 256 thr = 64 tokens/block; grid 512. LDS-aggregated lists.
__global__ __launch_bounds__(256) void gate_kernel(
    const float* __restrict__ x, const float* __restrict__ Wg,
    const float* __restrict__ bg,
    int* __restrict__ counts, int* __restrict__ lists, float* __restrict__ tokw,
    ushort* __restrict__ xb)
{
    __shared__ float sWg[DD * NE];   // 8 KiB
    __shared__ float sBg[NE];
    __shared__ int   sCnt[NE];
    __shared__ int   sBase[NE];
    const int tid = threadIdx.x;
    for (int i = tid; i < DD * NE; i += 256) sWg[i] = Wg[i];
    if (tid < NE) { sBg[tid] = bg[tid]; sCnt[tid] = 0; }
    __syncthreads();

    const int t = blockIdx.x * 64 + (tid >> 2);
    const int g = tid & 3;
    const float* xt = x + (size_t)t * DD;
    ushort*      xo = xb + (size_t)t * DD;

    float logits[NE];
    #pragma unroll
    for (int e = 0; e < NE; ++e) logits[e] = 0.0f;

    // lane g handles dims {g*4 + i*16 .. +3}, i=0..7 (quad covers 64B per iter)
    #pragma unroll
    for (int i = 0; i < 8; ++i) {
        const int d0 = g * 4 + i * 16;
        float4 v = ((const float4*)xt)[g + i * 4];
        const float* w0 = &sWg[(d0 + 0) * NE];
        const float* w1 = &sWg[(d0 + 1) * NE];
        const float* w2 = &sWg[(d0 + 2) * NE];
        const float* w3 = &sWg[(d0 + 3) * NE];
        #pragma unroll
        for (int e = 0; e < NE; ++e) {
            float a = logits[e];
            a = fmaf(v.x, w0[e], a);
            a = fmaf(v.y, w1[e], a);
            a = fmaf(v.z, w2[e], a);
            a = fmaf(v.w, w3[e], a);
            logits[e] = a;
        }
        ushort4 s; s.x = f2bf(v.x); s.y = f2bf(v.y); s.z = f2bf(v.z); s.w = f2bf(v.w);
        *(ushort4*)(xo + d0) = s;
    }

    // butterfly-sum partial logits over the 4-lane quad
    #pragma unroll
    for (int e = 0; e < NE; ++e) {
        float a = logits[e];
        a += __shfl_xor(a, 1);
        a += __shfl_xor(a, 2);
        logits[e] = a + sBg[e];
    }

    float m = logits[0];
    #pragma unroll
    for (int e = 1; e < NE; ++e) m = fmaxf(m, logits[e]);
    float Z = 0.0f;
    #pragma unroll
    for (int e = 0; e < NE; ++e) Z += expf(logits[e] - m);

    int i1 = 0; float l1 = logits[0];
    #pragma unroll
    for (int e = 1; e < NE; ++e) if (logits[e] > l1) { l1 = logits[e]; i1 = e; }
    int i2 = -1; float l2 = -3.4e38f;
    #pragma unroll
    for (int e = 0; e < NE; ++e) if (e != i1 && logits[e] > l2) { l2 = logits[e]; i2 = e; }

    int s1 = 0, s2 = 0;
    if (g == 0) {
        float p1 = expf(l1 - m) / Z;
        float p2 = expf(l2 - m) / Z;
        float s  = p1 + p2 + 1e-6f;
        tokw[t * 2 + 0] = p1 / s;
        tokw[t * 2 + 1] = p2 / s;
        s1 = atomicAdd(&sCnt[i1], 1);
        s2 = atomicAdd(&sCnt[i2], 1);
    }
    __syncthreads();
    if (tid < NE) sBase[tid] = atomicAdd(&counts[tid * CSTRIDE], sCnt[tid]);
    __syncthreads();
    if (g == 0) {
        lists[i1 * NTOK + sBase[i1] + s1] = t * 2 + 0;
        lists[i2 * NTOK + sBase[i2] + s2] = t * 2 + 1;
    }
}

// ---------------- Kernel 2: grouped expert GEMM via bf16 MFMA ----------------
// grid (NTOK/64, NE), block 256 = 4 waves; wave = 16 tokens x 128 outputs.
// No LDS, no barriers: A-frag = EwT[o][k] rows, B-frag = xb[tok][k] rows,
// both "8 contiguous k at row lane&15" (verified m92 B^T pattern).
// D is computed transposed (D[o][tok]) so each lane stores 4 contiguous output
// dims for ITS OWN token (store col == lane&15 == A/B row var), packed 8B bf16.
__global__ __launch_bounds__(256) void expert_kernel(
    const ushort* __restrict__ xb, const ushort* __restrict__ ewT,
    const int* __restrict__ counts, const int* __restrict__ lists,
    ushort* __restrict__ ybuf)
{
    const int e = blockIdx.y;
    const int count = counts[e * CSTRIDE];
    const int start = blockIdx.x * 64;
    if (start >= count) return;

    const int tid  = threadIdx.x;
    const int lane = tid & 63, wv = tid >> 6;
    const int row  = lane & 15;          // token within wave tile == D column
    const int kg   = lane >> 4;          // k-group 0..3

    const int idx = start + wv * 16 + row;
    const int en  = (idx < count) ? lists[e * NTOK + idx] : -1;
    const ushort* xrow = xb + (size_t)((en < 0 ? 0 : en) >> 1) * DD;

    bf16x8 xf[4];
    #pragma unroll
    for (int k = 0; k < 4; ++k)
        xf[k] = *(const bf16x8*)(xrow + k * 32 + kg * 8);

    const ushort* ewe = ewT + (size_t)e * DD * DD;
    f32x4 acc[8];
    #pragma unroll
    for (int n = 0; n < 8; ++n) acc[n] = (f32x4)(0.0f);

    #pragma unroll
    for (int n = 0; n < 8; ++n) {
        const ushort* er = ewe + (size_t)(n * 16 + row) * DD + kg * 8;
        #pragma unroll
        for (int k = 0; k < 4; ++k) {
            bf16x8 ef = *(const bf16x8*)(er + k * 32);
            acc[n] = __builtin_amdgcn_mfma_f32_16x16x32_bf16(ef, xf[k], acc[n], 0, 0, 0);
        }
    }

    if (en >= 0) {
        ushort* yr = ybuf + (size_t)en * DD + kg * 4;   // o = n*16 + kg*4 + reg
        #pragma unroll
        for (int n = 0; n < 8; ++n) {
            ushort4 s;
            s.x = f2bf(acc[n][0]); s.y = f2bf(acc[n][1]);
            s.z = f2bf(acc[n][2]); s.w = f2bf(acc[n][3]);
            *(ushort4*)(yr + n * 16) = s;
        }
    }
}

// ---------------- Kernel 3: combine (avg, var, consensus) -------------------
// block 256 = 4 waves; wave does 4 tokens. Lanes 0-31 load y1 (float4 dims),
// lanes 32-63 load y2; shfl_xor(32) exchange; coalesced float4 avg store.
__global__ __launch_bounds__(256) void combine_kernel(
    const ushort* __restrict__ ybuf, const float* __restrict__ tokw,
    float* __restrict__ avg_out, float* __restrict__ cons_out)
{
    const int tid = threadIdx.x;
    const int lane = tid & 63, wv = tid >> 6;
    const int half = lane >> 5, hl = lane & 31;
    const int t0 = blockIdx.x * 16 + wv * 4;

    #pragma unroll
    for (int j = 0; j < 4; ++j) {
        const int t = t0 + j;
        const float w1 = tokw[t * 2 + 0];
        const float w2 = tokw[t * 2 + 1];
        const float wo = half ? w2 : w1;
        const float wx = half ? w1 : w2;

        ushort4 raw = *(const ushort4*)(ybuf + (size_t)(t * 2 + half) * DD + hl * 4);
        float o0 = b2f(raw.x), o1 = b2f(raw.y), o2 = b2f(raw.z), o3 = b2f(raw.w);
        float x0 = __shfl_xor(o0, 32);
        float x1 = __shfl_xor(o1, 32);
        float x2 = __shfl_xor(o2, 32);
        float x3 = __shfl_xor(o3, 32);

        float a0 = wo * o0 + wx * x0;
        float a1 = wo * o1 + wx * x1;
        float a2 = wo * o2 + wx * x2;
        float a3 = wo * o3 + wx * x3;
        if (half == 0) {
            float4 av; av.x = a0; av.y = a1; av.z = a2; av.w = a3;
            ((float4*)(avg_out + (size_t)t * DD))[hl] = av;
        }
        float d0 = o0 - a0, d1 = o1 - a1, d2 = o2 - a2, d3 = o3 - a3;
        float e0 = x0 - a0, e1 = x1 - a1, e2 = x2 - a2, e3 = x3 - a3;
        float v = wo * (d0*d0 + d1*d1 + d2*d2 + d3*d3)
                + wx * (e0*e0 + e1*e1 + e2*e2 + e3*e3);
        v += __shfl_xor(v, 1);
        v += __shfl_xor(v, 2);
        v += __shfl_xor(v, 4);
        v += __shfl_xor(v, 8);
        v += __shfl_xor(v, 16);
        if (lane == 0) cons_out[t] = expf(-v * (1.0f / 128.0f));
    }
}

// ---------------- launcher ---------------------------------------------------
extern "C" void kernel_launch(void* const* d_in, const int* in_sizes, int n_in,
                              void* d_out, int out_size, void* d_ws, size_t ws_size,
                              hipStream_t stream)
{
    const float* x  = (const float*)d_in[0];
    const float* Wg = (const float*)d_in[1];
    const float* bg = (const float*)d_in[2];
    const float* Ew = (const float*)d_in[3];
    float* out = (float*)d_out;

    char* ws = (char*)d_ws;
    int*    counts = (int*)(ws + OFF_COUNTS);
    float*  tokw   = (float*)(ws + OFF_TOKW);
    int*    lists  = (int*)(ws + OFF_LISTS);
    ushort* xbuf   = (ushort*)(ws + OFF_XB);
    ushort* ewT    = (ushort*)(ws + OFF_EWT);
    ushort* ybuf   = (ushort*)(ws + OFF_YBUF);

    hipMemsetAsync(counts, 0, NE * CSTRIDE * sizeof(int), stream);

    ewt_kernel<<<256, 256, 0, stream>>>(Ew, ewT);
    gate_kernel<<<NTOK / 64, 256, 0, stream>>>(x, Wg, bg, counts, lists, tokw, xbuf);
    expert_kernel<<<dim3(NTOK / 64, NE), 256, 0, stream>>>(xbuf, ewT, counts, lists, ybuf);
    combine_kernel<<<NTOK / 16, 256, 0, stream>>>(ybuf, tokw, out, out + (size_t)NTOK * DD);
}